// Round 15
// baseline (547.704 us; speedup 1.0000x reference)
//
#include <hip/hip_runtime.h>
#include <hip/hip_bf16.h>
#include <hip/hip_fp16.h>
#include <math.h>

#define NDOC 4
#define CCC  1024
#define DDD  768
#define HHH  12
#define EEE  42
#define MMM  8
#define PPP  1024
#define NK   99
#define NPAD 112
#define NSLICE 48

typedef __attribute__((ext_vector_type(8))) short short8v;
typedef __attribute__((ext_vector_type(8))) _Float16 half8;
typedef __attribute__((ext_vector_type(4))) float floatx4;

__device__ __forceinline__ unsigned short f32_to_bf16u(float f) {
  return __builtin_bit_cast(unsigned short, __float2bfloat16(f));
}
__device__ __forceinline__ unsigned short f32_to_f16u(float f) {
  return __builtin_bit_cast(unsigned short, __float2half(f));
}

// ======== K1: fused prep (eemb | eatt | packW | seqT | prep_w) =============
__global__ __launch_bounds__(256) void k_prep(
    const float* __restrict__ seq, const float* __restrict__ att,
    const float* __restrict__ Wh, const float* __restrict__ Wt,
    const float* __restrict__ Wb,
    const int* __restrict__ pos, const int* __restrict__ mask,
    unsigned short* __restrict__ eembB, float* __restrict__ eatt,
    unsigned short* __restrict__ WhtB, unsigned short* __restrict__ seqTB,
    unsigned short* __restrict__ WpB) {
  const int bx = blockIdx.x;
  const int tid = threadIdx.x;
  if (bx < 168) {
    int e = bx % EEE, doc = bx / EEE;
    int base = (doc*EEE + e)*MMM;
    int p[MMM], mk[MMM];
#pragma unroll
    for (int m = 0; m < MMM; ++m) { p[m] = pos[base+m] + 1; mk[m] = mask[base+m]; }
    for (int d0 = tid; d0 < DDD; d0 += 256) {
      float v[MMM]; float mx = -INFINITY;
#pragma unroll
      for (int m = 0; m < MMM; ++m) {
        v[m] = seq[(doc*CCC + p[m])*DDD + d0];
        if (mk[m]) mx = fmaxf(mx, v[m]);
      }
      float s = 0.f;
#pragma unroll
      for (int m = 0; m < MMM; ++m) if (mk[m]) s += expf(v[m]-mx);
      eembB[(doc*EEE + e)*DDD + d0] = f32_to_bf16u(logf(s) + mx);
    }
  } else if (bx < 2184) {
    int b = bx - 168;
    int head = b % HHH, e = (b/HHH) % EEE, doc = b / (HHH*EEE);
    int base = (doc*EEE + e)*MMM;
    int j = tid * 4;
    float ax=0.f, ay=0.f, az=0.f, aw=0.f; float cnt = 0.f;
#pragma unroll
    for (int m = 0; m < MMM; ++m) {
      int mk = mask[base+m];
      cnt += (float)mk;
      if (mk) {
        int pp = pos[base+m] + 1;
        const float4 a = *(const float4*)&att[((size_t)(doc*HHH + head)*CCC + pp)*CCC + j];
        ax += a.x; ay += a.y; az += a.z; aw += a.w;
      }
    }
    float inv = 1.f / cnt;
    float4 o; o.x = ax*inv; o.y = ay*inv; o.z = az*inv; o.w = aw*inv;
    *(float4*)&eatt[((size_t)((doc*EEE + e)*HHH + head))*CCC + j] = o;
  } else if (bx < 3336) {
    int gid = (bx - 2184)*256 + tid;
    int half = gid >= 147456;
    int loc = half ? gid - 147456 : gid;
    const float* src = (half ? Wt : Wh) + (size_t)loc*8;
    float4 v0 = *(const float4*)src;
    float4 v1 = *(const float4*)(src+4);
    unsigned short o[8];
    o[0]=f32_to_bf16u(v0.x); o[1]=f32_to_bf16u(v0.y); o[2]=f32_to_bf16u(v0.z); o[3]=f32_to_bf16u(v0.w);
    o[4]=f32_to_bf16u(v1.x); o[5]=f32_to_bf16u(v1.y); o[6]=f32_to_bf16u(v1.z); o[7]=f32_to_bf16u(v1.w);
    *(uint4*)&WhtB[(size_t)half*1179648 + (size_t)loc*8] = *(const uint4*)o;
  } else if (bx < 4104) {
    __shared__ float tl[64][65];
    int b = bx - 3336;
    int d0 = (b % 12)*64, c0 = ((b/12) % 16)*64, doc = b / 192;
#pragma unroll
    for (int rep = 0; rep < 4; ++rep) {
      int cr = rep*16 + (tid >> 4);
      int d4 = (tid & 15) * 4;
      float4 v = *(const float4*)&seq[((size_t)doc*CCC + c0 + cr)*DDD + d0 + d4];
      tl[cr][d4+0]=v.x; tl[cr][d4+1]=v.y; tl[cr][d4+2]=v.z; tl[cr][d4+3]=v.w;
    }
    __syncthreads();
#pragma unroll
    for (int rep = 0; rep < 4; ++rep) {
      int dr = rep*16 + (tid >> 4);
      int c4 = (tid & 15) * 4;
      unsigned short o[4];
#pragma unroll
      for (int kq = 0; kq < 4; ++kq)
        o[kq] = f32_to_bf16u(tl[c4+kq][dr]);
      *(uint2*)&seqTB[((size_t)doc*DDD + d0 + dr)*CCC + c0 + c4] = *(const uint2*)o;
    }
  } else {
    int t = (bx - 4104)*256 + tid;
    int n  = t / 6144;
    int rem = t % 6144;
    int ki = rem >> 3;
    int j8 = (rem & 7) * 8;
    unsigned short o[8];
    if (n < NK) {
      const float* src = &Wb[(size_t)n*49152 + ki*64 + j8];
      float4 v0 = *(const float4*)src;
      float4 v1 = *(const float4*)(src+4);
      o[0]=f32_to_f16u(v0.x); o[1]=f32_to_f16u(v0.y); o[2]=f32_to_f16u(v0.z); o[3]=f32_to_f16u(v0.w);
      o[4]=f32_to_f16u(v1.x); o[5]=f32_to_f16u(v1.y); o[6]=f32_to_f16u(v1.z); o[7]=f32_to_f16u(v1.w);
    } else {
#pragma unroll
      for (int e=0;e<8;++e) o[e]=0;
    }
    int js = j8 >> 5, q = (j8 >> 3) & 3;
    int nt = n >> 4, lnn = n & 15;
    int c = ((js*7 + nt)*4 + q)*16 + lnn;
    *(uint4*)&WpB[(size_t)ki*7168 + c*8] = *(const uint4*)o;
  }
}

// ======== K2: ht_att phase 1 ===============================================
__global__ __launch_bounds__(256) void k_htatt1(const float* __restrict__ eatt,
    const int* __restrict__ hts, float* __restrict__ htU,
    float* __restrict__ Ssum) {
  __shared__ float tile[EEE*16*12];
  const int cg = blockIdx.x, doc = blockIdx.y;
  const int c0 = cg * 16;
  for (int idx = threadIdx.x; idx < EEE*16*12; idx += 256) {
    int e = idx / 192, rem = idx % 192, h = rem / 16, cc = rem % 16;
    tile[(e*16 + cc)*12 + h] =
        eatt[((size_t)((doc*EEE + e)*HHH + h))*CCC + c0 + cc];
  }
  __syncthreads();
  const int cc = threadIdx.x & 15;
  const int pg = threadIdx.x >> 4;
  for (int it = 0; it < 64; ++it) {
    int p = pg + it*16;
    int h0 = hts[(doc*PPP + p)*2 + 0];
    int t0 = hts[(doc*PPP + p)*2 + 1];
    const float* a = &tile[(h0*16 + cc)*12];
    const float* b = &tile[(t0*16 + cc)*12];
    float4 a0 = *(const float4*)a,     b0 = *(const float4*)b;
    float4 a1 = *(const float4*)(a+4), b1 = *(const float4*)(b+4);
    float4 a2 = *(const float4*)(a+8), b2 = *(const float4*)(b+8);
    float s = a0.x*b0.x + a0.y*b0.y + a0.z*b0.z + a0.w*b0.w
            + a1.x*b1.x + a1.y*b1.y + a1.z*b1.z + a1.w*b1.w
            + a2.x*b2.x + a2.y*b2.y + a2.z*b2.z + a2.w*b2.w;
    s *= (1.f/12.f);
    htU[((size_t)(doc*PPP + p))*CCC + c0 + cc] = s;
    float r = s;
    r += __shfl_xor(r, 1, 16);
    r += __shfl_xor(r, 2, 16);
    r += __shfl_xor(r, 4, 16);
    r += __shfl_xor(r, 8, 16);
    if (cc == 0) Ssum[((size_t)(doc*PPP + p))*64 + cg] = r;
  }
}

// ======== K3: ht_att phase 2 ===============================================
__global__ __launch_bounds__(256) void k_htnorm(const float* __restrict__ htU,
    const float* __restrict__ Ssum, unsigned short* __restrict__ htB) {
  __shared__ float sc_sh;
  const int b = blockIdx.x;
  const int lane = threadIdx.x;
  if (lane < 64) {
    float r = Ssum[(size_t)b*64 + lane];
    for (int off = 32; off > 0; off >>= 1) r += __shfl_down(r, off, 64);
    if (lane == 0) sc_sh = 1.f / (r + 1e-5f);
  }
  __syncthreads();
  float sc = sc_sh;
  float4 v = *(const float4*)&htU[(size_t)b*CCC + lane*4];
  unsigned short o[4];
  o[0] = f32_to_bf16u(v.x*sc); o[1] = f32_to_bf16u(v.y*sc);
  o[2] = f32_to_bf16u(v.z*sc); o[3] = f32_to_bf16u(v.w*sc);
  *(uint2*)&htB[(size_t)b*CCC + lane*4] = *(const uint2*)o;
}

// ======== K4: rs = htatt @ seq =============================================
__global__ __launch_bounds__(256) void k_rs_mfma(
    const unsigned short* __restrict__ htB,
    const unsigned short* __restrict__ seqTB,
    unsigned short* __restrict__ rsB) {
  __shared__ unsigned short A_l[4096];
  __shared__ unsigned short B_l[4096];
  const int n0 = blockIdx.x * 128;
  const int m0 = blockIdx.y * 128;
  const int doc = m0 >> 10;
  const int mloc = m0 & 1023;
  const int t = threadIdx.x;
  const int lane = t & 63;
  const int ln = lane & 15, q4 = lane >> 4;
  const int w = t >> 6;
  const int wr = w >> 1, wc = w & 1;

  const int r0 = t >> 2;
  const int koff = (t & 3) * 8;
  const unsigned short* srcA0 = htB + ((size_t)doc*CCC + mloc + r0)*CCC + koff;
  const unsigned short* srcA1 = htB + ((size_t)doc*CCC + mloc + r0 + 64)*CCC + koff;
  const unsigned short* srcB0 = seqTB + ((size_t)doc*DDD + n0 + r0)*CCC + koff;
  const unsigned short* srcB1 = seqTB + ((size_t)doc*DDD + n0 + r0 + 64)*CCC + koff;

  floatx4 acc[4][4];
#pragma unroll
  for (int i = 0; i < 4; ++i)
#pragma unroll
    for (int j = 0; j < 4; ++j) acc[i][j] = (floatx4){0.f,0.f,0.f,0.f};

  for (int k0 = 0; k0 < CCC; k0 += 32) {
    uint4 va0 = *(const uint4*)(srcA0 + k0);
    uint4 va1 = *(const uint4*)(srcA1 + k0);
    uint4 vb0 = *(const uint4*)(srcB0 + k0);
    uint4 vb1 = *(const uint4*)(srcB1 + k0);
    __syncthreads();
    *(uint4*)&A_l[(size_t)t*8]       = va0;
    *(uint4*)&A_l[(size_t)(t+256)*8] = va1;
    *(uint4*)&B_l[(size_t)t*8]       = vb0;
    *(uint4*)&B_l[(size_t)(t+256)*8] = vb1;
    __syncthreads();
    short8v a[4], b[4];
#pragma unroll
    for (int rt = 0; rt < 4; ++rt)
      a[rt] = *(const short8v*)&A_l[((wr*64 + rt*16 + ln)*4 + q4)*8];
#pragma unroll
    for (int nt = 0; nt < 4; ++nt)
      b[nt] = *(const short8v*)&B_l[((wc*64 + nt*16 + ln)*4 + q4)*8];
#pragma unroll
    for (int rt = 0; rt < 4; ++rt)
#pragma unroll
      for (int nt = 0; nt < 4; ++nt)
        acc[rt][nt] = __builtin_amdgcn_mfma_f32_16x16x32_bf16(a[rt], b[nt], acc[rt][nt], 0, 0, 0);
  }
#pragma unroll
  for (int rt = 0; rt < 4; ++rt)
#pragma unroll
    for (int nt = 0; nt < 4; ++nt) {
      int col = n0 + wc*64 + nt*16 + ln;
#pragma unroll
      for (int reg = 0; reg < 4; ++reg) {
        int row = m0 + wr*64 + rt*16 + q4*4 + reg;
        rsB[(size_t)row*DDD + col] = f32_to_bf16u(acc[rt][nt][reg]);
      }
    }
}

// ======== K5: heads GEMM ===================================================
__global__ __launch_bounds__(256) void k_heads_mfma(
    const unsigned short* __restrict__ eembB,
    const unsigned short* __restrict__ rsB,
    const int* __restrict__ hts,
    const unsigned short* __restrict__ WB,
    const float* __restrict__ bh, const float* __restrict__ bt,
    unsigned short* __restrict__ hsTB,
    unsigned short* __restrict__ tsbH) {
  __shared__ unsigned short A_l[4096];
  __shared__ unsigned short B_l[4096];
  __shared__ unsigned short T_l[128*144];
  const int which = blockIdx.z;
  const int n0 = blockIdx.x * 128;
  const int m0 = blockIdx.y * 128;
  const int doc = m0 >> 10;
  const int t = threadIdx.x;
  const int lane = t & 63;
  const int ln = lane & 15, q4 = lane >> 4;
  const int w = t >> 6;
  const int wr = w >> 1, wc = w & 1;

  const int r0 = t >> 2;
  const int koff = (t & 3) * 8;
  const int rgA0 = m0 + r0, rgA1 = m0 + r0 + 64;
  const int idx0 = hts[rgA0*2 + which];
  const int idx1 = hts[rgA1*2 + which];
  const unsigned short* srcE0 = eembB + (size_t)(doc*EEE + idx0)*DDD + koff;
  const unsigned short* srcE1 = eembB + (size_t)(doc*EEE + idx1)*DDD + koff;
  const unsigned short* srcR0 = rsB + (size_t)rgA0*DDD + koff;
  const unsigned short* srcR1 = rsB + (size_t)rgA1*DDD + koff;
  const unsigned short* WBz = WB + (size_t)which*1179648;
  const unsigned short* srcW0 = WBz + (size_t)(n0 + r0)*1536 + koff;
  const unsigned short* srcW1 = WBz + (size_t)(n0 + r0 + 64)*1536 + koff;

  floatx4 acc[4][4];
#pragma unroll
  for (int i = 0; i < 4; ++i)
#pragma unroll
    for (int j = 0; j < 4; ++j) acc[i][j] = (floatx4){0.f,0.f,0.f,0.f};

  for (int k0 = 0; k0 < 1536; k0 += 32) {
    uint4 va0 = (k0 < DDD) ? *(const uint4*)(srcE0 + k0) : *(const uint4*)(srcR0 + (k0 - DDD));
    uint4 va1 = (k0 < DDD) ? *(const uint4*)(srcE1 + k0) : *(const uint4*)(srcR1 + (k0 - DDD));
    uint4 vb0 = *(const uint4*)(srcW0 + k0);
    uint4 vb1 = *(const uint4*)(srcW1 + k0);
    __syncthreads();
    *(uint4*)&A_l[(size_t)t*8]       = va0;
    *(uint4*)&A_l[(size_t)(t+256)*8] = va1;
    *(uint4*)&B_l[(size_t)t*8]       = vb0;
    *(uint4*)&B_l[(size_t)(t+256)*8] = vb1;
    __syncthreads();
    short8v a[4], b[4];
#pragma unroll
    for (int rt = 0; rt < 4; ++rt)
      a[rt] = *(const short8v*)&A_l[((wr*64 + rt*16 + ln)*4 + q4)*8];
#pragma unroll
    for (int nt = 0; nt < 4; ++nt)
      b[nt] = *(const short8v*)&B_l[((wc*64 + nt*16 + ln)*4 + q4)*8];
#pragma unroll
    for (int rt = 0; rt < 4; ++rt)
#pragma unroll
      for (int nt = 0; nt < 4; ++nt)
        acc[rt][nt] = __builtin_amdgcn_mfma_f32_16x16x32_bf16(a[rt], b[nt], acc[rt][nt], 0, 0, 0);
  }
  const float* bias = which ? bt : bh;
  if (which == 0) {
#pragma unroll
    for (int rt = 0; rt < 4; ++rt)
#pragma unroll
      for (int nt = 0; nt < 4; ++nt) {
        int col = wc*64 + nt*16 + ln;
        float bsv = bias[n0 + col];
#pragma unroll
        for (int reg = 0; reg < 4; ++reg) {
          int row = wr*64 + rt*16 + q4*4 + reg;
          T_l[col*144 + row] = f32_to_f16u(tanhf(acc[rt][nt][reg] + bsv));
        }
      }
    __syncthreads();
#pragma unroll
    for (int iter = 0; iter < 8; ++iter) {
      int col = iter*16 + (t >> 4);
      int rblk = t & 15;
      uint4 v = *(const uint4*)&T_l[col*144 + rblk*8];
      *(uint4*)&hsTB[(size_t)(n0 + col)*4096 + m0 + rblk*8] = v;
    }
  } else {
#pragma unroll
    for (int rt = 0; rt < 4; ++rt)
#pragma unroll
      for (int nt = 0; nt < 4; ++nt) {
        int col = n0 + wc*64 + nt*16 + ln;
        float bsv = bias[col];
#pragma unroll
        for (int reg = 0; reg < 4; ++reg) {
          int row = m0 + wr*64 + rt*16 + q4*4 + reg;
          tsbH[(size_t)row*DDD + col] = f32_to_f16u(tanhf(acc[rt][nt][reg] + bsv));
        }
      }
  }
}

// ======== K6-ABL: template ablation of k_logits (writes to DEAD buffer) ====
// V=0 full | V=1 memory-pipeline only (no MFMA/A-gen) |
// V=2 compute only (slab staged once; no loop loads/barriers) |
// V=3 bare core (b ds_read + MFMA + stores; const A; no hsT/ts).
template<int V>
__global__ __launch_bounds__(256) void k_abl(
    const unsigned short* __restrict__ hsT,
    const unsigned short* __restrict__ tsbH,
    const unsigned short* __restrict__ Wp,
    unsigned short* __restrict__ P) {
  __shared__ unsigned short hsT_l[16*256];
  __shared__ unsigned short slab[2*7168];
  const int bid = blockIdx.x;
  const int wg = (bid & 7)*96 + (bid >> 3);
  const int slice = wg >> 4;
  const int mgroup = wg & 15;
  const int kbase = slice * 16;
  const int nb = kbase >> 6;
  const int t = threadIdx.x;
  const int w = t >> 6;
  const int lane = t & 63;
  const int ln = lane & 15;
  const int q = lane >> 4;
  const int m0w = mgroup*256 + w*64;

  if (V != 3) {
#pragma unroll
    for (int rep = 0; rep < 2; ++rep) {
      int c16 = t + rep*256;
      int ii = c16 >> 5;
      int c8 = (c16 & 31) * 8;
      uint4 v = *(const uint4*)&hsT[(size_t)(kbase + ii)*4096 + mgroup*256 + c8];
      *(uint4*)&hsT_l[ii*256 + c8] = v;
    }
  }

  __half2 tsr2[4][2][4];
  if (V != 3) {
#pragma unroll
    for (int rt = 0; rt < 4; ++rt) {
      int row = m0w + rt*16 + ln;
#pragma unroll
      for (int js = 0; js < 2; ++js) {
        uint4 v = *(const uint4*)&tsbH[(size_t)row*DDD + nb*64 + js*32 + q*8];
        tsr2[rt][js][0] = __builtin_bit_cast(__half2, v.x);
        tsr2[rt][js][1] = __builtin_bit_cast(__half2, v.y);
        tsr2[rt][js][2] = __builtin_bit_cast(__half2, v.z);
        tsr2[rt][js][3] = __builtin_bit_cast(__half2, v.w);
      }
    }
  }

  floatx4 acc[4][7];
#pragma unroll
  for (int rt = 0; rt < 4; ++rt)
#pragma unroll
    for (int nt = 0; nt < 7; ++nt)
      acc[rt][nt] = (floatx4){0.f,0.f,0.f,0.f};

  // prologue slab staging (all variants stage once)
  uint4 wreg[7];
#pragma unroll
  for (int r = 0; r < 7; ++r)
    wreg[r] = *(const uint4*)&Wp[(size_t)kbase*7168 + (t + r*256)*8];
#pragma unroll
  for (int r = 0; r < 7; ++r)
    *(uint4*)&slab[(t + r*256)*8] = wreg[r];
  __syncthreads();

  const unsigned int one_h2 = 0x3c003c00u;  // {1.0h, 1.0h}
  for (int ks = 0; ks < 8; ++ks) {
    if ((V == 0 || V == 1) && ks < 7) {
      int kin = kbase + (ks + 1)*2;
#pragma unroll
      for (int r = 0; r < 7; ++r)
        wreg[r] = *(const uint4*)&Wp[(size_t)kin*7168 + (t + r*256)*8];
    }
#pragma unroll
    for (int il = 0; il < 2; ++il) {
      int ii = ks*2 + il;
      __half2 hh[4];
      if (V != 3) {
#pragma unroll
        for (int rt = 0; rt < 4; ++rt) {
          unsigned short hb = hsT_l[ii*256 + w*64 + rt*16 + ln];
          hh[rt] = __half2half2(__ushort_as_half(hb));
        }
      } else {
#pragma unroll
        for (int rt = 0; rt < 4; ++rt)
          hh[rt] = __builtin_bit_cast(__half2, one_h2);
      }
#pragma unroll
      for (int js = 0; js < 2; ++js) {
        half8 b[7];
#pragma unroll
        for (int nt = 0; nt < 7; ++nt)
          b[nt] = __builtin_bit_cast(half8,
              *(const short8v*)&slab[((size_t)il*896 + (js*7 + nt)*64 + lane)*8]);
        if (V == 1) {
#pragma unroll
          for (int nt = 0; nt < 7; ++nt)
            asm volatile("" :: "v"(b[nt]));       // keep loads live, no MFMA
#pragma unroll
          for (int rt = 0; rt < 4; ++rt)
            asm volatile("" :: "v"(hh[rt]));
        } else {
          half8 a[4];
#pragma unroll
          for (int rt = 0; rt < 4; ++rt) {
            uint4 au;
            if (V == 3) {
              au.x = one_h2; au.y = one_h2; au.z = one_h2; au.w = one_h2;
            } else {
              au.x = __builtin_bit_cast(unsigned int, __hmul2(hh[rt], tsr2[rt][0 ? 0 : (js)][0]));
              au.y = __builtin_bit_cast(unsigned int, __hmul2(hh[rt], tsr2[rt][js][1]));
              au.z = __builtin_bit_cast(unsigned int, __hmul2(hh[rt], tsr2[rt][js][2]));
              au.w = __builtin_bit_cast(unsigned int, __hmul2(hh[rt], tsr2[rt][js][3]));
            }
            a[rt] = __builtin_bit_cast(half8, au);
          }
#pragma unroll
          for (int nt = 0; nt < 7; ++nt)
#pragma unroll
            for (int rt = 0; rt < 4; ++rt)
              acc[rt][nt] = __builtin_amdgcn_mfma_f32_16x16x32_f16(a[rt], b[nt], acc[rt][nt], 0, 0, 0);
        }
      }
    }
    if ((V == 0 || V == 1) && ks < 7) {
      __syncthreads();
#pragma unroll
      for (int r = 0; r < 7; ++r)
        *(uint4*)&slab[(t + r*256)*8] = wreg[r];
      __syncthreads();
    }
  }

  unsigned short* Ps = P + (size_t)slice*(4096*NPAD);
#pragma unroll
  for (int nt = 0; nt < 7; ++nt) {
    int col = nt*16 + ln;
#pragma unroll
    for (int rt = 0; rt < 4; ++rt) {
#pragma unroll
      for (int reg = 0; reg < 4; ++reg) {
        int row = m0w + rt*16 + q*4 + reg;
        __builtin_nontemporal_store(f32_to_f16u(acc[rt][nt][reg]),
                                    &Ps[(size_t)row*NPAD + col]);
      }
    }
  }
}

// ======== K6: REAL logits kernel (identical to passing R14 version) ========
__global__ __launch_bounds__(256) void k_logits_mfma(
    const unsigned short* __restrict__ hsT,
    const unsigned short* __restrict__ tsbH,
    const unsigned short* __restrict__ Wp,
    unsigned short* __restrict__ P) {
  __shared__ unsigned short hsT_l[16*256];
  __shared__ unsigned short slab[2*7168];
  const int bid = blockIdx.x;
  const int wg = (bid & 7)*96 + (bid >> 3);
  const int slice = wg >> 4;
  const int mgroup = wg & 15;
  const int kbase = slice * 16;
  const int nb = kbase >> 6;
  const int t = threadIdx.x;
  const int w = t >> 6;
  const int lane = t & 63;
  const int ln = lane & 15;
  const int q = lane >> 4;
  const int m0w = mgroup*256 + w*64;

#pragma unroll
  for (int rep = 0; rep < 2; ++rep) {
    int c16 = t + rep*256;
    int ii = c16 >> 5;
    int c8 = (c16 & 31) * 8;
    uint4 v = *(const uint4*)&hsT[(size_t)(kbase + ii)*4096 + mgroup*256 + c8];
    *(uint4*)&hsT_l[ii*256 + c8] = v;
  }

  __half2 tsr2[4][2][4];
#pragma unroll
  for (int rt = 0; rt < 4; ++rt) {
    int row = m0w + rt*16 + ln;
#pragma unroll
    for (int js = 0; js < 2; ++js) {
      uint4 v = *(const uint4*)&tsbH[(size_t)row*DDD + nb*64 + js*32 + q*8];
      tsr2[rt][js][0] = __builtin_bit_cast(__half2, v.x);
      tsr2[rt][js][1] = __builtin_bit_cast(__half2, v.y);
      tsr2[rt][js][2] = __builtin_bit_cast(__half2, v.z);
      tsr2[rt][js][3] = __builtin_bit_cast(__half2, v.w);
    }
  }

  floatx4 acc[4][7];
#pragma unroll
  for (int rt = 0; rt < 4; ++rt)
#pragma unroll
    for (int nt = 0; nt < 7; ++nt)
      acc[rt][nt] = (floatx4){0.f,0.f,0.f,0.f};

  uint4 wreg[7];
#pragma unroll
  for (int r = 0; r < 7; ++r)
    wreg[r] = *(const uint4*)&Wp[(size_t)kbase*7168 + (t + r*256)*8];
#pragma unroll
  for (int r = 0; r < 7; ++r)
    *(uint4*)&slab[(t + r*256)*8] = wreg[r];
  __syncthreads();

  for (int ks = 0; ks < 8; ++ks) {
    if (ks < 7) {
      int kin = kbase + (ks + 1)*2;
#pragma unroll
      for (int r = 0; r < 7; ++r)
        wreg[r] = *(const uint4*)&Wp[(size_t)kin*7168 + (t + r*256)*8];
    }
#pragma unroll
    for (int il = 0; il < 2; ++il) {
      int ii = ks*2 + il;
      __half2 hh[4];
#pragma unroll
      for (int rt = 0; rt < 4; ++rt) {
        unsigned short hb = hsT_l[ii*256 + w*64 + rt*16 + ln];
        hh[rt] = __half2half2(__ushort_as_half(hb));
      }
#pragma unroll
      for (int js = 0; js < 2; ++js) {
        half8 b[7];
#pragma unroll
        for (int nt = 0; nt < 7; ++nt)
          b[nt] = __builtin_bit_cast(half8,
              *(const short8v*)&slab[((size_t)il*896 + (js*7 + nt)*64 + lane)*8]);
        half8 a[4];
#pragma unroll
        for (int rt = 0; rt < 4; ++rt) {
          uint4 au;
          au.x = __builtin_bit_cast(unsigned int, __hmul2(hh[rt], tsr2[rt][js][0]));
          au.y = __builtin_bit_cast(unsigned int, __hmul2(hh[rt], tsr2[rt][js][1]));
          au.z = __builtin_bit_cast(unsigned int, __hmul2(hh[rt], tsr2[rt][js][2]));
          au.w = __builtin_bit_cast(unsigned int, __hmul2(hh[rt], tsr2[rt][js][3]));
          a[rt] = __builtin_bit_cast(half8, au);
        }
#pragma unroll
        for (int nt = 0; nt < 7; ++nt)
#pragma unroll
          for (int rt = 0; rt < 4; ++rt)
            acc[rt][nt] = __builtin_amdgcn_mfma_f32_16x16x32_f16(a[rt], b[nt], acc[rt][nt], 0, 0, 0);
      }
    }
    if (ks < 7) {
      __syncthreads();
#pragma unroll
      for (int r = 0; r < 7; ++r)
        *(uint4*)&slab[(t + r*256)*8] = wreg[r];
      __syncthreads();
    }
  }

  unsigned short* Ps = P + (size_t)slice*(4096*NPAD);
#pragma unroll
  for (int nt = 0; nt < 7; ++nt) {
    int col = nt*16 + ln;
#pragma unroll
    for (int rt = 0; rt < 4; ++rt) {
#pragma unroll
      for (int reg = 0; reg < 4; ++reg) {
        int row = m0w + rt*16 + q*4 + reg;
        __builtin_nontemporal_store(f32_to_f16u(acc[rt][nt][reg]),
                                    &Ps[(size_t)row*NPAD + col]);
      }
    }
  }
}

// ======== K7: reduce 48 fp16 partial slices -> logits fp32 =================
__global__ __launch_bounds__(256) void k_logred(const unsigned short* __restrict__ P,
    float* __restrict__ out) {
  int idx = blockIdx.x*256 + threadIdx.x;
  int r = idx / NPAD;
  int c = idx % NPAD;
  if (c >= NK) return;
  float s = 0.f;
#pragma unroll 8
  for (int sl = 0; sl < NSLICE; ++sl)
    s += __half2float(__ushort_as_half(P[(size_t)sl*(4096*NPAD) + idx]));
  out[(size_t)r*NK + c] = s;
}

extern "C" void kernel_launch(void* const* d_in, const int* in_sizes, int n_in,
                              void* d_out, int out_size, void* d_ws, size_t ws_size,
                              hipStream_t stream) {
  const float* seq  = (const float*)d_in[0];
  const float* att  = (const float*)d_in[1];
  const float* Wh   = (const float*)d_in[2];
  const float* bh   = (const float*)d_in[3];
  const float* Wt   = (const float*)d_in[4];
  const float* bt   = (const float*)d_in[5];
  const float* Wb   = (const float*)d_in[6];
  const int* pos    = (const int*)d_in[7];
  const int* mask   = (const int*)d_in[8];
  const int* hts    = (const int*)d_in[9];
  float* out = (float*)d_out;

  float* ws = (float*)d_ws;
  float*          eatt  = ws;                                 // 2,064,384 f
  float*          htU   = ws + 2064384;                       // 4,194,304 f
  float*          Ssum  = ws + 6258688;                       //   262,144 f
  unsigned short* htB   = (unsigned short*)(ws + 6520832);    // 4,194,304 us
  unsigned short* eembB = (unsigned short*)(ws + 8617984);    //   129,024 us
  unsigned short* seqTB = (unsigned short*)(ws + 8682496);    // 3,145,728 us
  unsigned short* WhtB  = (unsigned short*)(ws + 10255360);   // 2,359,296 us
  unsigned short* rsB   = (unsigned short*)(ws + 11435008);   // 3,145,728 us
  unsigned short* hsTB  = (unsigned short*)(ws + 13007872);   // 3,145,728 us
  unsigned short* tsbH  = (unsigned short*)(ws + 14580736);   // 3,145,728 us
  unsigned short* WpB   = (unsigned short*)(ws + 16153600);   // 5,505,024 us
  unsigned short* Pp    = (unsigned short*)(ws + 18906112);   // 22,020,096 us
  unsigned short* Pdead = (unsigned short*)(ws + 29916160);   // 22,020,096 us (ablation sink)

  k_prep<<<dim3(6792), 256, 0, stream>>>(seq, att, Wh, Wt, Wb, pos, mask,
                                         eembB, eatt, WhtB, seqTB, WpB);
  k_htatt1<<<dim3(64, NDOC), 256, 0, stream>>>(eatt, hts, htU, Ssum);
  k_htnorm<<<dim3(NDOC*PPP), 256, 0, stream>>>(htU, Ssum, htB);
  k_rs_mfma<<<dim3(6, 32), 256, 0, stream>>>(htB, seqTB, rsB);
  k_heads_mfma<<<dim3(6, 32, 2), 256, 0, stream>>>(eembB, rsB, hts, WhtB, bh, bt, hsTB, tsbH);
  // ---- ablation probes (dead output, deterministic) ----
  k_abl<0><<<dim3(48*16), 256, 0, stream>>>(hsTB, tsbH, WpB, Pdead);
  k_abl<1><<<dim3(48*16), 256, 0, stream>>>(hsTB, tsbH, WpB, Pdead);
  k_abl<2><<<dim3(48*16), 256, 0, stream>>>(hsTB, tsbH, WpB, Pdead);
  k_abl<3><<<dim3(48*16), 256, 0, stream>>>(hsTB, tsbH, WpB, Pdead);
  // ---- real ----
  k_logits_mfma<<<dim3(48*16), 256, 0, stream>>>(hsTB, tsbH, WpB, Pp);
  k_logred<<<dim3(4096*NPAD/256), 256, 0, stream>>>(Pp, out);
}

// Round 16
// 213.172 us; speedup vs baseline: 2.5693x; 2.5693x over previous
//
#include <hip/hip_runtime.h>
#include <hip/hip_bf16.h>
#include <hip/hip_fp16.h>
#include <math.h>

#define NDOC 4
#define CCC  1024
#define DDD  768
#define HHH  12
#define EEE  42
#define MMM  8
#define PPP  1024
#define NK   99
#define NPAD 112
#define NSLICE 48

typedef __attribute__((ext_vector_type(8))) short short8v;
typedef __attribute__((ext_vector_type(8))) _Float16 half8;
typedef __attribute__((ext_vector_type(4))) float floatx4;

__device__ __forceinline__ unsigned short f32_to_bf16u(float f) {
  return __builtin_bit_cast(unsigned short, __float2bfloat16(f));
}
__device__ __forceinline__ unsigned short f32_to_f16u(float f) {
  return __builtin_bit_cast(unsigned short, __float2half(f));
}
// async global->LDS 16B: per-lane global src, wave-uniform LDS base (+lane*16 in HW)
__device__ __forceinline__ void async_copy16(const unsigned short* g, unsigned short* l) {
  __builtin_amdgcn_global_load_lds(
      (const __attribute__((address_space(1))) unsigned int*)g,
      (__attribute__((address_space(3))) unsigned int*)l, 16, 0, 0);
}

// ======== K1: fused prep (eemb | eatt | packW | seqT | prep_w) =============
__global__ __launch_bounds__(256) void k_prep(
    const float* __restrict__ seq, const float* __restrict__ att,
    const float* __restrict__ Wh, const float* __restrict__ Wt,
    const float* __restrict__ Wb,
    const int* __restrict__ pos, const int* __restrict__ mask,
    unsigned short* __restrict__ eembB, float* __restrict__ eatt,
    unsigned short* __restrict__ WhtB, unsigned short* __restrict__ seqTB,
    unsigned short* __restrict__ WpB) {
  const int bx = blockIdx.x;
  const int tid = threadIdx.x;
  if (bx < 168) {
    int e = bx % EEE, doc = bx / EEE;
    int base = (doc*EEE + e)*MMM;
    int p[MMM], mk[MMM];
#pragma unroll
    for (int m = 0; m < MMM; ++m) { p[m] = pos[base+m] + 1; mk[m] = mask[base+m]; }
    for (int d0 = tid; d0 < DDD; d0 += 256) {
      float v[MMM]; float mx = -INFINITY;
#pragma unroll
      for (int m = 0; m < MMM; ++m) {
        v[m] = seq[(doc*CCC + p[m])*DDD + d0];
        if (mk[m]) mx = fmaxf(mx, v[m]);
      }
      float s = 0.f;
#pragma unroll
      for (int m = 0; m < MMM; ++m) if (mk[m]) s += expf(v[m]-mx);
      eembB[(doc*EEE + e)*DDD + d0] = f32_to_bf16u(logf(s) + mx);
    }
  } else if (bx < 2184) {
    int b = bx - 168;
    int head = b % HHH, e = (b/HHH) % EEE, doc = b / (HHH*EEE);
    int base = (doc*EEE + e)*MMM;
    int j = tid * 4;
    float ax=0.f, ay=0.f, az=0.f, aw=0.f; float cnt = 0.f;
#pragma unroll
    for (int m = 0; m < MMM; ++m) {
      int mk = mask[base+m];
      cnt += (float)mk;
      if (mk) {
        int pp = pos[base+m] + 1;
        const float4 a = *(const float4*)&att[((size_t)(doc*HHH + head)*CCC + pp)*CCC + j];
        ax += a.x; ay += a.y; az += a.z; aw += a.w;
      }
    }
    float inv = 1.f / cnt;
    float4 o; o.x = ax*inv; o.y = ay*inv; o.z = az*inv; o.w = aw*inv;
    *(float4*)&eatt[((size_t)((doc*EEE + e)*HHH + head))*CCC + j] = o;
  } else if (bx < 3336) {
    int gid = (bx - 2184)*256 + tid;
    int half = gid >= 147456;
    int loc = half ? gid - 147456 : gid;
    const float* src = (half ? Wt : Wh) + (size_t)loc*8;
    float4 v0 = *(const float4*)src;
    float4 v1 = *(const float4*)(src+4);
    unsigned short o[8];
    o[0]=f32_to_bf16u(v0.x); o[1]=f32_to_bf16u(v0.y); o[2]=f32_to_bf16u(v0.z); o[3]=f32_to_bf16u(v0.w);
    o[4]=f32_to_bf16u(v1.x); o[5]=f32_to_bf16u(v1.y); o[6]=f32_to_bf16u(v1.z); o[7]=f32_to_bf16u(v1.w);
    *(uint4*)&WhtB[(size_t)half*1179648 + (size_t)loc*8] = *(const uint4*)o;
  } else if (bx < 4104) {
    __shared__ float tl[64][65];
    int b = bx - 3336;
    int d0 = (b % 12)*64, c0 = ((b/12) % 16)*64, doc = b / 192;
#pragma unroll
    for (int rep = 0; rep < 4; ++rep) {
      int cr = rep*16 + (tid >> 4);
      int d4 = (tid & 15) * 4;
      float4 v = *(const float4*)&seq[((size_t)doc*CCC + c0 + cr)*DDD + d0 + d4];
      tl[cr][d4+0]=v.x; tl[cr][d4+1]=v.y; tl[cr][d4+2]=v.z; tl[cr][d4+3]=v.w;
    }
    __syncthreads();
#pragma unroll
    for (int rep = 0; rep < 4; ++rep) {
      int dr = rep*16 + (tid >> 4);
      int c4 = (tid & 15) * 4;
      unsigned short o[4];
#pragma unroll
      for (int kq = 0; kq < 4; ++kq)
        o[kq] = f32_to_bf16u(tl[c4+kq][dr]);
      *(uint2*)&seqTB[((size_t)doc*DDD + d0 + dr)*CCC + c0 + c4] = *(const uint2*)o;
    }
  } else {
    int t = (bx - 4104)*256 + tid;
    int n  = t / 6144;
    int rem = t % 6144;
    int ki = rem >> 3;
    int j8 = (rem & 7) * 8;
    unsigned short o[8];
    if (n < NK) {
      const float* src = &Wb[(size_t)n*49152 + ki*64 + j8];
      float4 v0 = *(const float4*)src;
      float4 v1 = *(const float4*)(src+4);
      o[0]=f32_to_f16u(v0.x); o[1]=f32_to_f16u(v0.y); o[2]=f32_to_f16u(v0.z); o[3]=f32_to_f16u(v0.w);
      o[4]=f32_to_f16u(v1.x); o[5]=f32_to_f16u(v1.y); o[6]=f32_to_f16u(v1.z); o[7]=f32_to_f16u(v1.w);
    } else {
#pragma unroll
      for (int e=0;e<8;++e) o[e]=0;
    }
    int js = j8 >> 5, q = (j8 >> 3) & 3;
    int nt = n >> 4, lnn = n & 15;
    int c = ((js*7 + nt)*4 + q)*16 + lnn;
    *(uint4*)&WpB[(size_t)ki*7168 + c*8] = *(const uint4*)o;
  }
}

// ======== K2: ht_att phase 1 ===============================================
__global__ __launch_bounds__(256) void k_htatt1(const float* __restrict__ eatt,
    const int* __restrict__ hts, float* __restrict__ htU,
    float* __restrict__ Ssum) {
  __shared__ float tile[EEE*16*12];
  const int cg = blockIdx.x, doc = blockIdx.y;
  const int c0 = cg * 16;
  for (int idx = threadIdx.x; idx < EEE*16*12; idx += 256) {
    int e = idx / 192, rem = idx % 192, h = rem / 16, cc = rem % 16;
    tile[(e*16 + cc)*12 + h] =
        eatt[((size_t)((doc*EEE + e)*HHH + h))*CCC + c0 + cc];
  }
  __syncthreads();
  const int cc = threadIdx.x & 15;
  const int pg = threadIdx.x >> 4;
  for (int it = 0; it < 64; ++it) {
    int p = pg + it*16;
    int h0 = hts[(doc*PPP + p)*2 + 0];
    int t0 = hts[(doc*PPP + p)*2 + 1];
    const float* a = &tile[(h0*16 + cc)*12];
    const float* b = &tile[(t0*16 + cc)*12];
    float4 a0 = *(const float4*)a,     b0 = *(const float4*)b;
    float4 a1 = *(const float4*)(a+4), b1 = *(const float4*)(b+4);
    float4 a2 = *(const float4*)(a+8), b2 = *(const float4*)(b+8);
    float s = a0.x*b0.x + a0.y*b0.y + a0.z*b0.z + a0.w*b0.w
            + a1.x*b1.x + a1.y*b1.y + a1.z*b1.z + a1.w*b1.w
            + a2.x*b2.x + a2.y*b2.y + a2.z*b2.z + a2.w*b2.w;
    s *= (1.f/12.f);
    htU[((size_t)(doc*PPP + p))*CCC + c0 + cc] = s;
    float r = s;
    r += __shfl_xor(r, 1, 16);
    r += __shfl_xor(r, 2, 16);
    r += __shfl_xor(r, 4, 16);
    r += __shfl_xor(r, 8, 16);
    if (cc == 0) Ssum[((size_t)(doc*PPP + p))*64 + cg] = r;
  }
}

// ======== K3: ht_att phase 2 ===============================================
__global__ __launch_bounds__(256) void k_htnorm(const float* __restrict__ htU,
    const float* __restrict__ Ssum, unsigned short* __restrict__ htB) {
  __shared__ float sc_sh;
  const int b = blockIdx.x;
  const int lane = threadIdx.x;
  if (lane < 64) {
    float r = Ssum[(size_t)b*64 + lane];
    for (int off = 32; off > 0; off >>= 1) r += __shfl_down(r, off, 64);
    if (lane == 0) sc_sh = 1.f / (r + 1e-5f);
  }
  __syncthreads();
  float sc = sc_sh;
  float4 v = *(const float4*)&htU[(size_t)b*CCC + lane*4];
  unsigned short o[4];
  o[0] = f32_to_bf16u(v.x*sc); o[1] = f32_to_bf16u(v.y*sc);
  o[2] = f32_to_bf16u(v.z*sc); o[3] = f32_to_bf16u(v.w*sc);
  *(uint2*)&htB[(size_t)b*CCC + lane*4] = *(const uint2*)o;
}

// ======== K4: rs = htatt @ seq =============================================
__global__ __launch_bounds__(256) void k_rs_mfma(
    const unsigned short* __restrict__ htB,
    const unsigned short* __restrict__ seqTB,
    unsigned short* __restrict__ rsB) {
  __shared__ unsigned short A_l[4096];
  __shared__ unsigned short B_l[4096];
  const int n0 = blockIdx.x * 128;
  const int m0 = blockIdx.y * 128;
  const int doc = m0 >> 10;
  const int mloc = m0 & 1023;
  const int t = threadIdx.x;
  const int lane = t & 63;
  const int ln = lane & 15, q4 = lane >> 4;
  const int w = t >> 6;
  const int wr = w >> 1, wc = w & 1;

  const int r0 = t >> 2;
  const int koff = (t & 3) * 8;
  const unsigned short* srcA0 = htB + ((size_t)doc*CCC + mloc + r0)*CCC + koff;
  const unsigned short* srcA1 = htB + ((size_t)doc*CCC + mloc + r0 + 64)*CCC + koff;
  const unsigned short* srcB0 = seqTB + ((size_t)doc*DDD + n0 + r0)*CCC + koff;
  const unsigned short* srcB1 = seqTB + ((size_t)doc*DDD + n0 + r0 + 64)*CCC + koff;

  floatx4 acc[4][4];
#pragma unroll
  for (int i = 0; i < 4; ++i)
#pragma unroll
    for (int j = 0; j < 4; ++j) acc[i][j] = (floatx4){0.f,0.f,0.f,0.f};

  for (int k0 = 0; k0 < CCC; k0 += 32) {
    uint4 va0 = *(const uint4*)(srcA0 + k0);
    uint4 va1 = *(const uint4*)(srcA1 + k0);
    uint4 vb0 = *(const uint4*)(srcB0 + k0);
    uint4 vb1 = *(const uint4*)(srcB1 + k0);
    __syncthreads();
    *(uint4*)&A_l[(size_t)t*8]       = va0;
    *(uint4*)&A_l[(size_t)(t+256)*8] = va1;
    *(uint4*)&B_l[(size_t)t*8]       = vb0;
    *(uint4*)&B_l[(size_t)(t+256)*8] = vb1;
    __syncthreads();
    short8v a[4], b[4];
#pragma unroll
    for (int rt = 0; rt < 4; ++rt)
      a[rt] = *(const short8v*)&A_l[((wr*64 + rt*16 + ln)*4 + q4)*8];
#pragma unroll
    for (int nt = 0; nt < 4; ++nt)
      b[nt] = *(const short8v*)&B_l[((wc*64 + nt*16 + ln)*4 + q4)*8];
#pragma unroll
    for (int rt = 0; rt < 4; ++rt)
#pragma unroll
      for (int nt = 0; nt < 4; ++nt)
        acc[rt][nt] = __builtin_amdgcn_mfma_f32_16x16x32_bf16(a[rt], b[nt], acc[rt][nt], 0, 0, 0);
  }
#pragma unroll
  for (int rt = 0; rt < 4; ++rt)
#pragma unroll
    for (int nt = 0; nt < 4; ++nt) {
      int col = n0 + wc*64 + nt*16 + ln;
#pragma unroll
      for (int reg = 0; reg < 4; ++reg) {
        int row = m0 + wr*64 + rt*16 + q4*4 + reg;
        rsB[(size_t)row*DDD + col] = f32_to_bf16u(acc[rt][nt][reg]);
      }
    }
}

// ======== K5: heads GEMM ===================================================
__global__ __launch_bounds__(256) void k_heads_mfma(
    const unsigned short* __restrict__ eembB,
    const unsigned short* __restrict__ rsB,
    const int* __restrict__ hts,
    const unsigned short* __restrict__ WB,
    const float* __restrict__ bh, const float* __restrict__ bt,
    unsigned short* __restrict__ hsTB,
    unsigned short* __restrict__ tsbH) {
  __shared__ unsigned short A_l[4096];
  __shared__ unsigned short B_l[4096];
  __shared__ unsigned short T_l[128*144];
  const int which = blockIdx.z;
  const int n0 = blockIdx.x * 128;
  const int m0 = blockIdx.y * 128;
  const int doc = m0 >> 10;
  const int t = threadIdx.x;
  const int lane = t & 63;
  const int ln = lane & 15, q4 = lane >> 4;
  const int w = t >> 6;
  const int wr = w >> 1, wc = w & 1;

  const int r0 = t >> 2;
  const int koff = (t & 3) * 8;
  const int rgA0 = m0 + r0, rgA1 = m0 + r0 + 64;
  const int idx0 = hts[rgA0*2 + which];
  const int idx1 = hts[rgA1*2 + which];
  const unsigned short* srcE0 = eembB + (size_t)(doc*EEE + idx0)*DDD + koff;
  const unsigned short* srcE1 = eembB + (size_t)(doc*EEE + idx1)*DDD + koff;
  const unsigned short* srcR0 = rsB + (size_t)rgA0*DDD + koff;
  const unsigned short* srcR1 = rsB + (size_t)rgA1*DDD + koff;
  const unsigned short* WBz = WB + (size_t)which*1179648;
  const unsigned short* srcW0 = WBz + (size_t)(n0 + r0)*1536 + koff;
  const unsigned short* srcW1 = WBz + (size_t)(n0 + r0 + 64)*1536 + koff;

  floatx4 acc[4][4];
#pragma unroll
  for (int i = 0; i < 4; ++i)
#pragma unroll
    for (int j = 0; j < 4; ++j) acc[i][j] = (floatx4){0.f,0.f,0.f,0.f};

  for (int k0 = 0; k0 < 1536; k0 += 32) {
    uint4 va0 = (k0 < DDD) ? *(const uint4*)(srcE0 + k0) : *(const uint4*)(srcR0 + (k0 - DDD));
    uint4 va1 = (k0 < DDD) ? *(const uint4*)(srcE1 + k0) : *(const uint4*)(srcR1 + (k0 - DDD));
    uint4 vb0 = *(const uint4*)(srcW0 + k0);
    uint4 vb1 = *(const uint4*)(srcW1 + k0);
    __syncthreads();
    *(uint4*)&A_l[(size_t)t*8]       = va0;
    *(uint4*)&A_l[(size_t)(t+256)*8] = va1;
    *(uint4*)&B_l[(size_t)t*8]       = vb0;
    *(uint4*)&B_l[(size_t)(t+256)*8] = vb1;
    __syncthreads();
    short8v a[4], b[4];
#pragma unroll
    for (int rt = 0; rt < 4; ++rt)
      a[rt] = *(const short8v*)&A_l[((wr*64 + rt*16 + ln)*4 + q4)*8];
#pragma unroll
    for (int nt = 0; nt < 4; ++nt)
      b[nt] = *(const short8v*)&B_l[((wc*64 + nt*16 + ln)*4 + q4)*8];
#pragma unroll
    for (int rt = 0; rt < 4; ++rt)
#pragma unroll
      for (int nt = 0; nt < 4; ++nt)
        acc[rt][nt] = __builtin_amdgcn_mfma_f32_16x16x32_bf16(a[rt], b[nt], acc[rt][nt], 0, 0, 0);
  }
  const float* bias = which ? bt : bh;
  if (which == 0) {
#pragma unroll
    for (int rt = 0; rt < 4; ++rt)
#pragma unroll
      for (int nt = 0; nt < 4; ++nt) {
        int col = wc*64 + nt*16 + ln;
        float bsv = bias[n0 + col];
#pragma unroll
        for (int reg = 0; reg < 4; ++reg) {
          int row = wr*64 + rt*16 + q4*4 + reg;
          T_l[col*144 + row] = f32_to_f16u(tanhf(acc[rt][nt][reg] + bsv));
        }
      }
    __syncthreads();
#pragma unroll
    for (int iter = 0; iter < 8; ++iter) {
      int col = iter*16 + (t >> 4);
      int rblk = t & 15;
      uint4 v = *(const uint4*)&T_l[col*144 + rblk*8];
      *(uint4*)&hsTB[(size_t)(n0 + col)*4096 + m0 + rblk*8] = v;
    }
  } else {
#pragma unroll
    for (int rt = 0; rt < 4; ++rt)
#pragma unroll
      for (int nt = 0; nt < 4; ++nt) {
        int col = n0 + wc*64 + nt*16 + ln;
        float bsv = bias[col];
#pragma unroll
        for (int reg = 0; reg < 4; ++reg) {
          int row = m0 + wr*64 + rt*16 + q4*4 + reg;
          tsbH[(size_t)row*DDD + col] = f32_to_f16u(tanhf(acc[rt][nt][reg] + bsv));
        }
      }
  }
}

// ======== K6: logits partials — async global_load_lds dbuf slab ===========
// grid 768 (XCD-banded): slice (K=16 ki) x mgroup (256 rows). 4 waves.
// Slab (2 ki) double-buffered, staged via global_load_lds width-16 (no VGPR
// round-trip): issue next slab async -> MFMA on current -> vmcnt(0)+barrier.
// Fragment-major Wp is linear in chunk index: LDS dest wave-uniform, global
// src per-lane contiguous (the legal global_load_lds pattern).
__global__ __launch_bounds__(256) void k_logits_mfma(
    const unsigned short* __restrict__ hsT,   // [768][4096] fp16
    const unsigned short* __restrict__ tsbH,  // [4096][768] fp16
    const unsigned short* __restrict__ Wp,    // [768 ki][896 c][8] fp16
    unsigned short* __restrict__ P) {         // [48][4096][112] fp16
  __shared__ unsigned short hsT_l[16*256];    // 8 KB
  __shared__ unsigned short slab[2][14336];   // dbuf 2-ki slabs, 57.3 KB
  const int bid = blockIdx.x;
  const int wg = (bid & 7)*96 + (bid >> 3);   // XCD banding (768 % 8 == 0)
  const int slice = wg >> 4;
  const int mgroup = wg & 15;
  const int kbase = slice * 16;
  const int nb = kbase >> 6;
  const int t = threadIdx.x;
  const int w = t >> 6;
  const int lane = t & 63;
  const int ln = lane & 15;
  const int q = lane >> 4;
  const int m0w = mgroup*256 + w*64;

  // async-stage slab[0]: 1792 chunks, 7 per thread; per (wave,r) one
  // global_load_lds: lds base (r*256+w*64)*16B uniform, src per-lane.
  {
    const unsigned short* gsrc = Wp + (size_t)kbase*7168 + (size_t)(w*64 + lane)*8;
#pragma unroll
    for (int r = 0; r < 7; ++r)
      async_copy16(gsrc + r*2048, &slab[0][(r*256 + w*64)*8]);
  }

  // stage hsT tile [16 ki][256 r] (regular stores; drained by same barrier)
#pragma unroll
  for (int rep = 0; rep < 2; ++rep) {
    int c16 = t + rep*256;
    int ii = c16 >> 5;
    int c8 = (c16 & 31) * 8;
    uint4 v = *(const uint4*)&hsT[(size_t)(kbase + ii)*4096 + mgroup*256 + c8];
    *(uint4*)&hsT_l[ii*256 + c8] = v;
  }

  // ts fragment rows (fp16 pairs in registers)
  __half2 tsr2[4][2][4];
#pragma unroll
  for (int rt = 0; rt < 4; ++rt) {
    int row = m0w + rt*16 + ln;
#pragma unroll
    for (int js = 0; js < 2; ++js) {
      uint4 v = *(const uint4*)&tsbH[(size_t)row*DDD + nb*64 + js*32 + q*8];
      tsr2[rt][js][0] = __builtin_bit_cast(__half2, v.x);
      tsr2[rt][js][1] = __builtin_bit_cast(__half2, v.y);
      tsr2[rt][js][2] = __builtin_bit_cast(__half2, v.z);
      tsr2[rt][js][3] = __builtin_bit_cast(__half2, v.w);
    }
  }

  floatx4 acc[4][7];
#pragma unroll
  for (int rt = 0; rt < 4; ++rt)
#pragma unroll
    for (int nt = 0; nt < 7; ++nt)
      acc[rt][nt] = (floatx4){0.f,0.f,0.f,0.f};

  asm volatile("s_waitcnt vmcnt(0)" ::: "memory");  // slab[0] async writes done
  __syncthreads();

  for (int ks = 0; ks < 8; ++ks) {
    const int cur = ks & 1;
    // issue next slab's async copies (no registers; fly under MFMA)
    if (ks < 7) {
      int kin = kbase + (ks + 1)*2;
      const unsigned short* gsrc = Wp + (size_t)kin*7168 + (size_t)(w*64 + lane)*8;
#pragma unroll
      for (int r = 0; r < 7; ++r)
        async_copy16(gsrc + r*2048, &slab[cur ^ 1][(r*256 + w*64)*8]);
    }
#pragma unroll
    for (int il = 0; il < 2; ++il) {
      int ii = ks*2 + il;
      __half2 hh[4];
#pragma unroll
      for (int rt = 0; rt < 4; ++rt) {
        unsigned short hb = hsT_l[ii*256 + w*64 + rt*16 + ln];
        hh[rt] = __half2half2(__ushort_as_half(hb));
      }
#pragma unroll
      for (int js = 0; js < 2; ++js) {
        half8 b[7];
#pragma unroll
        for (int nt = 0; nt < 7; ++nt)
          b[nt] = __builtin_bit_cast(half8,
              *(const short8v*)&slab[cur][((size_t)il*896 + (js*7 + nt)*64 + lane)*8]);
        half8 a[4];
#pragma unroll
        for (int rt = 0; rt < 4; ++rt) {
          uint4 au;
          au.x = __builtin_bit_cast(unsigned int, __hmul2(hh[rt], tsr2[rt][js][0]));
          au.y = __builtin_bit_cast(unsigned int, __hmul2(hh[rt], tsr2[rt][js][1]));
          au.z = __builtin_bit_cast(unsigned int, __hmul2(hh[rt], tsr2[rt][js][2]));
          au.w = __builtin_bit_cast(unsigned int, __hmul2(hh[rt], tsr2[rt][js][3]));
          a[rt] = __builtin_bit_cast(half8, au);
        }
#pragma unroll
        for (int nt = 0; nt < 7; ++nt)
#pragma unroll
          for (int rt = 0; rt < 4; ++rt)
            acc[rt][nt] = __builtin_amdgcn_mfma_f32_16x16x32_f16(a[rt], b[nt], acc[rt][nt], 0, 0, 0);
      }
    }
    asm volatile("s_waitcnt vmcnt(0)" ::: "memory");  // next slab landed
    __syncthreads();
  }

  unsigned short* Ps = P + (size_t)slice*(4096*NPAD);
#pragma unroll
  for (int nt = 0; nt < 7; ++nt) {
    int col = nt*16 + ln;
#pragma unroll
    for (int rt = 0; rt < 4; ++rt) {
#pragma unroll
      for (int reg = 0; reg < 4; ++reg) {
        int row = m0w + rt*16 + q*4 + reg;
        __builtin_nontemporal_store(f32_to_f16u(acc[rt][nt][reg]),
                                    &Ps[(size_t)row*NPAD + col]);
      }
    }
  }
}

// ======== K7: reduce 48 fp16 partial slices -> logits fp32 =================
__global__ __launch_bounds__(256) void k_logred(const unsigned short* __restrict__ P,
    float* __restrict__ out) {
  int idx = blockIdx.x*256 + threadIdx.x;
  int r = idx / NPAD;
  int c = idx % NPAD;
  if (c >= NK) return;
  float s = 0.f;
#pragma unroll 8
  for (int sl = 0; sl < NSLICE; ++sl)
    s += __half2float(__ushort_as_half(P[(size_t)sl*(4096*NPAD) + idx]));
  out[(size_t)r*NK + c] = s;
}

extern "C" void kernel_launch(void* const* d_in, const int* in_sizes, int n_in,
                              void* d_out, int out_size, void* d_ws, size_t ws_size,
                              hipStream_t stream) {
  const float* seq  = (const float*)d_in[0];
  const float* att  = (const float*)d_in[1];
  const float* Wh   = (const float*)d_in[2];
  const float* bh   = (const float*)d_in[3];
  const float* Wt   = (const float*)d_in[4];
  const float* bt   = (const float*)d_in[5];
  const float* Wb   = (const float*)d_in[6];
  const int* pos    = (const int*)d_in[7];
  const int* mask   = (const int*)d_in[8];
  const int* hts    = (const int*)d_in[9];
  float* out = (float*)d_out;

  float* ws = (float*)d_ws;
  float*          eatt  = ws;                                 // 2,064,384 f
  float*          htU   = ws + 2064384;                       // 4,194,304 f
  float*          Ssum  = ws + 6258688;                       //   262,144 f
  unsigned short* htB   = (unsigned short*)(ws + 6520832);    // 4,194,304 us
  unsigned short* eembB = (unsigned short*)(ws + 8617984);    //   129,024 us
  unsigned short* seqTB = (unsigned short*)(ws + 8682496);    // 3,145,728 us
  unsigned short* WhtB  = (unsigned short*)(ws + 10255360);   // 2,359,296 us
  unsigned short* rsB   = (unsigned short*)(ws + 11435008);   // 3,145,728 us
  unsigned short* hsTB  = (unsigned short*)(ws + 13007872);   // 3,145,728 us
  unsigned short* tsbH  = (unsigned short*)(ws + 14580736);   // 3,145,728 us
  unsigned short* WpB   = (unsigned short*)(ws + 16153600);   // 5,505,024 us
  unsigned short* Pp    = (unsigned short*)(ws + 18906112);   // 22,020,096 us

  k_prep<<<dim3(6792), 256, 0, stream>>>(seq, att, Wh, Wt, Wb, pos, mask,
                                         eembB, eatt, WhtB, seqTB, WpB);
  k_htatt1<<<dim3(64, NDOC), 256, 0, stream>>>(eatt, hts, htU, Ssum);
  k_htnorm<<<dim3(NDOC*PPP), 256, 0, stream>>>(htU, Ssum, htB);
  k_rs_mfma<<<dim3(6, 32), 256, 0, stream>>>(htB, seqTB, rsB);
  k_heads_mfma<<<dim3(6, 32, 2), 256, 0, stream>>>(eembB, rsB, hts, WhtB, bh, bt, hsTB, tsbH);
  k_logits_mfma<<<dim3(48*16), 256, 0, stream>>>(hsTB, tsbH, WpB, Pp);
  k_logred<<<dim3(4096*NPAD/256), 256, 0, stream>>>(Pp, out);
}